// Round 15
// baseline (147.009 us; speedup 1.0000x reference)
//
#include <hip/hip_runtime.h>
#include <hip/hip_fp16.h>
#include <math.h>

#define NUM_H 4
#define HD 64
#define DIN 128
#define NEG_SLOPE 0.2f
#define LOG2E 1.4426950408889634f

#define NBK 512   // dst buckets (256 nodes each; 100k nodes -> 391 used)
#define BSH 8     // bucket shift
#define NCH 256   // edge chunks (R13 measured-best; 1024 regressed via write-amp)
#define SRCB 17   // src fits 17 bits (n < 131072); loc uses bits 17..24

typedef _Float16 half8 __attribute__((ext_vector_type(8)));
typedef float f32x4 __attribute__((ext_vector_type(4)));

__device__ inline half8 pack8(float4 a, float4 b) {
  half8 h;
  h[0] = (_Float16)a.x; h[1] = (_Float16)a.y;
  h[2] = (_Float16)a.z; h[3] = (_Float16)a.w;
  h[4] = (_Float16)b.x; h[5] = (_Float16)b.y;
  h[6] = (_Float16)b.z; h[7] = (_Float16)b.w;
  return h;
}

// Pass 1: per-chunk LDS histogram over NBK dst-buckets (int4-vectorized),
// mat[chunk][bucket].
__global__ __launch_bounds__(256) void k_hist(const int* __restrict__ dst,
                                              int* __restrict__ mat, int e) {
  __shared__ int h[NBK];
  for (int i = threadIdx.x; i < NBK; i += 256) h[i] = 0;
  __syncthreads();
  const int chunk = (e + NCH - 1) / NCH;
  const int lo = blockIdx.x * chunk;
  const int hi = min(e, lo + chunk);
  const int lo4 = min(hi, (lo + 3) & ~3);
  const int hi4 = (hi & ~3) < lo4 ? lo4 : (hi & ~3);
  for (int i = lo + threadIdx.x; i < lo4; i += 256)
    atomicAdd(&h[dst[i] >> BSH], 1);
  for (int i = lo4 + threadIdx.x * 4; i < hi4; i += 1024) {
    int4 d4 = *reinterpret_cast<const int4*>(dst + i);
    atomicAdd(&h[d4.x >> BSH], 1);
    atomicAdd(&h[d4.y >> BSH], 1);
    atomicAdd(&h[d4.z >> BSH], 1);
    atomicAdd(&h[d4.w >> BSH], 1);
  }
  for (int i = hi4 + threadIdx.x; i < hi; i += 256)
    atomicAdd(&h[dst[i] >> BSH], 1);
  __syncthreads();
  for (int i = threadIdx.x; i < NBK; i += 256)
    mat[blockIdx.x * NBK + i] = h[i];
}

// Pass 2a (1 block per bucket): scan the bucket's NCH chunk-counts
// (LDS Hillis-Steele) -> per-(chunk,bucket) within-bucket starts + total.
__global__ __launch_bounds__(256) void k_scanA(int* __restrict__ mat,
                                               int* __restrict__ tot) {
  __shared__ int sm[NCH];
  const int b = blockIdx.x;
  const int t = threadIdx.x;
  int v = mat[t * NBK + b];
  sm[t] = v;
  __syncthreads();
  for (int off = 1; off < NCH; off <<= 1) {
    int x = (t >= off) ? sm[t - off] : 0;
    __syncthreads();
    sm[t] += x;
    __syncthreads();
  }
  mat[t * NBK + b] = sm[t] - v;  // exclusive within bucket
  if (t == NCH - 1) tot[b] = sm[t];
}

// Pass 2b (1 tiny block): exclusive scan of NBK bucket totals -> bbase.
__global__ __launch_bounds__(NBK) void k_scanB(const int* __restrict__ tot,
                                               int* __restrict__ bbase,
                                               int* __restrict__ offs,
                                               int e, int n) {
  __shared__ int sm[NBK];
  const int t = threadIdx.x;
  int v = tot[t];
  sm[t] = v;
  __syncthreads();
  for (int off = 1; off < NBK; off <<= 1) {
    int x = (t >= off) ? sm[t - off] : 0;
    __syncthreads();
    sm[t] += x;
    __syncthreads();
  }
  bbase[t] = sm[t] - v;
  if (t == NBK - 1) bbase[NBK] = sm[t];
  if (t == 0) offs[n] = e;
}

// ------- fused: bucket scatter (blocks < NCH) + projection via MFMA --------
// R13 measured-best: latency-bound bucket blocks hide under proj's short
// MFMA blocks. Bucket: per-chunk scatter of packed (loc<<17|src) via LDS
// cursors. Proj: z = feat @ W^T f16/MFMA, one wave = 16x64, no LDS staging;
// el/er pre-scaled by log2e.
__global__ __launch_bounds__(256) void k_proj_bucket(
    const float* __restrict__ feat, const float* __restrict__ Wm,
    const float* __restrict__ attn, const int* __restrict__ src,
    const int* __restrict__ dst, const int* __restrict__ mat,
    const int* __restrict__ bbase, __half* __restrict__ zh,
    float* __restrict__ el, float* __restrict__ er,
    int* __restrict__ bkt, int n, int e) {
  __shared__ int cur[NBK];
  if ((int)blockIdx.x < NCH) {
    const int cb = blockIdx.x;
    for (int i = threadIdx.x; i < NBK; i += 256)
      cur[i] = bbase[i] + mat[cb * NBK + i];
    __syncthreads();
    const int chunk = (e + NCH - 1) / NCH;
    const int lo = cb * chunk;
    const int hi = min(e, lo + chunk);
    const int lo4 = min(hi, (lo + 3) & ~3);
    const int hi4 = (hi & ~3) < lo4 ? lo4 : (hi & ~3);
    for (int i = lo + threadIdx.x; i < lo4; i += 256) {
      int d = dst[i];
      int p = atomicAdd(&cur[d >> BSH], 1);
      bkt[p] = ((d & ((1 << BSH) - 1)) << SRCB) | src[i];
    }
    for (int i = lo4 + threadIdx.x * 4; i < hi4; i += 1024) {
      int4 d4 = *reinterpret_cast<const int4*>(dst + i);
      int4 s4 = *reinterpret_cast<const int4*>(src + i);
      int p0 = atomicAdd(&cur[d4.x >> BSH], 1);
      bkt[p0] = ((d4.x & ((1 << BSH) - 1)) << SRCB) | s4.x;
      int p1 = atomicAdd(&cur[d4.y >> BSH], 1);
      bkt[p1] = ((d4.y & ((1 << BSH) - 1)) << SRCB) | s4.y;
      int p2 = atomicAdd(&cur[d4.z >> BSH], 1);
      bkt[p2] = ((d4.z & ((1 << BSH) - 1)) << SRCB) | s4.z;
      int p3 = atomicAdd(&cur[d4.w >> BSH], 1);
      bkt[p3] = ((d4.w & ((1 << BSH) - 1)) << SRCB) | s4.w;
    }
    for (int i = hi4 + threadIdx.x; i < hi; i += 256) {
      int d = dst[i];
      int p = atomicAdd(&cur[d >> BSH], 1);
      bkt[p] = ((d & ((1 << BSH) - 1)) << SRCB) | src[i];
    }
    return;
  }

  const int pb = (int)blockIdx.x - NCH;
  const int lane = threadIdx.x & 63;
  const int wv = threadIdx.x >> 6;
  const int l15 = lane & 15;
  const int g = lane >> 4;
  const int base = pb * 64 + wv * 16;

  half8 bf[4][4];  // [kt][j]
#pragma unroll
  for (int j = 0; j < 4; ++j) {
    const float* wp = Wm + (j * 16 + l15) * 128 + g * 8;
#pragma unroll
    for (int kt = 0; kt < 4; ++kt) {
      float4 w0 = *(const float4*)(wp + kt * 32);
      float4 w1 = *(const float4*)(wp + kt * 32 + 4);
      bf[kt][j] = pack8(w0, w1);
    }
  }

  int arow = base + l15;
  if (arow > n - 1) arow = n - 1;
  const float* fp = feat + (size_t)arow * 128 + g * 8;
  half8 af[4];
#pragma unroll
  for (int kt = 0; kt < 4; ++kt) {
    float4 a0 = *(const float4*)(fp + kt * 32);
    float4 a1 = *(const float4*)(fp + kt * 32 + 4);
    af[kt] = pack8(a0, a1);
  }

  f32x4 acc[4] = {{0.f,0.f,0.f,0.f},{0.f,0.f,0.f,0.f},
                  {0.f,0.f,0.f,0.f},{0.f,0.f,0.f,0.f}};
#pragma unroll
  for (int kt = 0; kt < 4; ++kt)
#pragma unroll
    for (int j = 0; j < 4; ++j)
      acc[j] = __builtin_amdgcn_mfma_f32_16x16x32_f16(af[kt], bf[kt][j], acc[j], 0, 0, 0);

  float a0v[4], a1v[4];
#pragma unroll
  for (int j = 0; j < 4; ++j) {
    a0v[j] = attn[j * 16 + l15];
    a1v[j] = attn[64 + j * 16 + l15];
  }
#pragma unroll
  for (int r = 0; r < 4; ++r) {
    int row = base + g * 4 + r;
    bool ok = row < n;
#pragma unroll
    for (int j = 0; j < 4; ++j) {
      float v = acc[j][r];
      if (ok) zh[(size_t)row * 64 + j * 16 + l15] = __float2half_rn(v);
      float pl = v * a0v[j];
      float pr = v * a1v[j];
#pragma unroll
      for (int o = 8; o >= 1; o >>= 1) {
        pl += __shfl_xor(pl, o, 16);
        pr += __shfl_xor(pr, o, 16);
      }
      if (ok && l15 == 0) {
        el[row * 4 + j] = pl * LOG2E;
        er[row * 4 + j] = pr * LOG2E;
      }
    }
  }
}

// Pass 4: one block per bucket (256 nodes): LDS node-histogram -> 8-step
// butterfly scan (1 node/thread) -> offs (coalesced) -> LDS-cursor scatter.
__global__ __launch_bounds__(256) void k_csr(
    const int* __restrict__ bkt, const int* __restrict__ bbase,
    int* __restrict__ offs, int* __restrict__ csr, int n) {
  __shared__ int h[1 << BSH];
  __shared__ int pre[1 << BSH];
  const int b = blockIdx.x;
  const int base = bbase[b];
  const int cnt = bbase[b + 1] - base;
  const int nlo = b << BSH;
  const int t = threadIdx.x;

  h[t] = 0;
  __syncthreads();
  for (int i = t; i < cnt; i += 256)
    atomicAdd(&h[bkt[base + i] >> SRCB], 1);
  __syncthreads();

  int v = h[t];
  pre[t] = v;
  __syncthreads();
  for (int off = 1; off < 256; off <<= 1) {
    int x = (t >= off) ? pre[t - off] : 0;
    __syncthreads();
    pre[t] += x;
    __syncthreads();
  }
  int excl = pre[t] - v;
  if (nlo + t < n) offs[nlo + t] = base + excl;
  h[t] = excl;  // reuse as cursor
  __syncthreads();
  for (int i = t; i < cnt; i += 256) {
    int w = bkt[base + i];
    int p = atomicAdd(&h[w >> SRCB], 1);
    csr[base + p] = w & ((1 << SRCB) - 1);
  }
}

// ---------------- fused segment softmax + weighted aggregate ----------------
// TWO NODES PER WAVE (nA, nB = nA + nwaves): the joint loop issues both
// nodes' 8-edge blocks together -> 2x independent gather chains per wave to
// fill latency gaps (R13 k_gat: VALU 52% / HBM 33% / occ 66% = chain-stalled).
// Same lane layout (h, slot, dp), persistent grid-stride, step-2 tails,
// raw v_exp_f32 on log2e-prescaled logits.
__global__ __launch_bounds__(256) void k_gat(
    const __half2* __restrict__ zh, const float* __restrict__ el,
    const float* __restrict__ er, const int* __restrict__ offs,
    const int* __restrict__ csr, const float* __restrict__ bias,
    float* __restrict__ out, int n, int nwaves) {
  const int lane = threadIdx.x & 63;
  const int h = lane >> 4;
  const int slot = (lane >> 3) & 1;
  const int dp = lane & 7;
  const int zoff = h * 8 + dp;
  const int gw = (blockIdx.x * 256 + threadIdx.x) >> 6;

  const float2 b2 = reinterpret_cast<const float2*>(bias)[zoff];

  for (int nA = gw; nA < n; nA += 2 * nwaves) {
    const int nB = nA + nwaves;
    const bool hasB = nB < n;
    const int begA = offs[nA], endA = offs[nA + 1];
    const float erhA = er[nA * 4 + h];
    int begB = 0, endB = 0;
    float erhB = 0.f;
    if (hasB) {
      begB = offs[nB];
      endB = offs[nB + 1];
      erhB = er[nB * 4 + h];
    }
    float denA = 0.f, axA = 0.f, ayA = 0.f;
    float denB = 0.f, axB = 0.f, ayB = 0.f;
    int pbA = begA, pbB = begB;

    // joint loop: 16 edges (8 per node) in flight
    while (pbA + 8 <= endA && pbB + 8 <= endB) {
      const int qA = pbA + slot, qB = pbB + slot;
      int a0 = csr[qA], a1 = csr[qA + 2], a2 = csr[qA + 4], a3 = csr[qA + 6];
      int c0 = csr[qB], c1 = csr[qB + 2], c2 = csr[qB + 4], c3 = csr[qB + 6];
      float xa0 = el[a0 * 4 + h] + erhA;
      float xa1 = el[a1 * 4 + h] + erhA;
      float xa2 = el[a2 * 4 + h] + erhA;
      float xa3 = el[a3 * 4 + h] + erhA;
      float xb0 = el[c0 * 4 + h] + erhB;
      float xb1 = el[c1 * 4 + h] + erhB;
      float xb2 = el[c2 * 4 + h] + erhB;
      float xb3 = el[c3 * 4 + h] + erhB;
      xa0 = fmaxf(xa0, xa0 * NEG_SLOPE);
      xa1 = fmaxf(xa1, xa1 * NEG_SLOPE);
      xa2 = fmaxf(xa2, xa2 * NEG_SLOPE);
      xa3 = fmaxf(xa3, xa3 * NEG_SLOPE);
      xb0 = fmaxf(xb0, xb0 * NEG_SLOPE);
      xb1 = fmaxf(xb1, xb1 * NEG_SLOPE);
      xb2 = fmaxf(xb2, xb2 * NEG_SLOPE);
      xb3 = fmaxf(xb3, xb3 * NEG_SLOPE);
      float ea0 = __builtin_amdgcn_exp2f(xa0);
      float ea1 = __builtin_amdgcn_exp2f(xa1);
      float ea2 = __builtin_amdgcn_exp2f(xa2);
      float ea3 = __builtin_amdgcn_exp2f(xa3);
      float eb0 = __builtin_amdgcn_exp2f(xb0);
      float eb1 = __builtin_amdgcn_exp2f(xb1);
      float eb2 = __builtin_amdgcn_exp2f(xb2);
      float eb3 = __builtin_amdgcn_exp2f(xb3);
      float2 za0 = __half22float2(zh[a0 * 32 + zoff]);
      float2 za1 = __half22float2(zh[a1 * 32 + zoff]);
      float2 za2 = __half22float2(zh[a2 * 32 + zoff]);
      float2 za3 = __half22float2(zh[a3 * 32 + zoff]);
      float2 zb0 = __half22float2(zh[c0 * 32 + zoff]);
      float2 zb1 = __half22float2(zh[c1 * 32 + zoff]);
      float2 zb2 = __half22float2(zh[c2 * 32 + zoff]);
      float2 zb3 = __half22float2(zh[c3 * 32 + zoff]);
      denA += ea0 + ea1 + ea2 + ea3;
      axA += ea0 * za0.x + ea1 * za1.x + ea2 * za2.x + ea3 * za3.x;
      ayA += ea0 * za0.y + ea1 * za1.y + ea2 * za2.y + ea3 * za3.y;
      denB += eb0 + eb1 + eb2 + eb3;
      axB += eb0 * zb0.x + eb1 * zb1.x + eb2 * zb2.x + eb3 * zb3.x;
      ayB += eb0 * zb0.y + eb1 * zb1.y + eb2 * zb2.y + eb3 * zb3.y;
      pbA += 8;
      pbB += 8;
    }
    // drain A
    for (; pbA + 8 <= endA; pbA += 8) {
      const int q = pbA + slot;
      int s0 = csr[q], s1 = csr[q + 2], s2 = csr[q + 4], s3 = csr[q + 6];
      float x0 = el[s0 * 4 + h] + erhA;
      float x1 = el[s1 * 4 + h] + erhA;
      float x2 = el[s2 * 4 + h] + erhA;
      float x3 = el[s3 * 4 + h] + erhA;
      x0 = fmaxf(x0, x0 * NEG_SLOPE);
      x1 = fmaxf(x1, x1 * NEG_SLOPE);
      x2 = fmaxf(x2, x2 * NEG_SLOPE);
      x3 = fmaxf(x3, x3 * NEG_SLOPE);
      float e0 = __builtin_amdgcn_exp2f(x0);
      float e1 = __builtin_amdgcn_exp2f(x1);
      float e2 = __builtin_amdgcn_exp2f(x2);
      float e3 = __builtin_amdgcn_exp2f(x3);
      float2 z0 = __half22float2(zh[s0 * 32 + zoff]);
      float2 z1 = __half22float2(zh[s1 * 32 + zoff]);
      float2 z2 = __half22float2(zh[s2 * 32 + zoff]);
      float2 z3 = __half22float2(zh[s3 * 32 + zoff]);
      denA += e0 + e1 + e2 + e3;
      axA += e0 * z0.x + e1 * z1.x + e2 * z2.x + e3 * z3.x;
      ayA += e0 * z0.y + e1 * z1.y + e2 * z2.y + e3 * z3.y;
    }
    for (int q = pbA + slot; q < endA; q += 2) {
      int s0 = csr[q];
      float x0 = el[s0 * 4 + h] + erhA;
      x0 = fmaxf(x0, x0 * NEG_SLOPE);
      float e0 = __builtin_amdgcn_exp2f(x0);
      float2 z0 = __half22float2(zh[s0 * 32 + zoff]);
      denA += e0;
      axA += e0 * z0.x;
      ayA += e0 * z0.y;
    }
    // drain B
    for (; pbB + 8 <= endB; pbB += 8) {
      const int q = pbB + slot;
      int s0 = csr[q], s1 = csr[q + 2], s2 = csr[q + 4], s3 = csr[q + 6];
      float x0 = el[s0 * 4 + h] + erhB;
      float x1 = el[s1 * 4 + h] + erhB;
      float x2 = el[s2 * 4 + h] + erhB;
      float x3 = el[s3 * 4 + h] + erhB;
      x0 = fmaxf(x0, x0 * NEG_SLOPE);
      x1 = fmaxf(x1, x1 * NEG_SLOPE);
      x2 = fmaxf(x2, x2 * NEG_SLOPE);
      x3 = fmaxf(x3, x3 * NEG_SLOPE);
      float e0 = __builtin_amdgcn_exp2f(x0);
      float e1 = __builtin_amdgcn_exp2f(x1);
      float e2 = __builtin_amdgcn_exp2f(x2);
      float e3 = __builtin_amdgcn_exp2f(x3);
      float2 z0 = __half22float2(zh[s0 * 32 + zoff]);
      float2 z1 = __half22float2(zh[s1 * 32 + zoff]);
      float2 z2 = __half22float2(zh[s2 * 32 + zoff]);
      float2 z3 = __half22float2(zh[s3 * 32 + zoff]);
      denB += e0 + e1 + e2 + e3;
      axB += e0 * z0.x + e1 * z1.x + e2 * z2.x + e3 * z3.x;
      ayB += e0 * z0.y + e1 * z1.y + e2 * z2.y + e3 * z3.y;
    }
    for (int q = pbB + slot; q < endB; q += 2) {
      int s0 = csr[q];
      float x0 = el[s0 * 4 + h] + erhB;
      x0 = fmaxf(x0, x0 * NEG_SLOPE);
      float e0 = __builtin_amdgcn_exp2f(x0);
      float2 z0 = __half22float2(zh[s0 * 32 + zoff]);
      denB += e0;
      axB += e0 * z0.x;
      ayB += e0 * z0.y;
    }

    denA += __shfl_xor(denA, 8);
    axA += __shfl_xor(axA, 8);
    ayA += __shfl_xor(ayA, 8);
    denB += __shfl_xor(denB, 8);
    axB += __shfl_xor(axB, 8);
    ayB += __shfl_xor(ayB, 8);
    if (slot == 0) {
      float dA = denA <= 0.f ? 1.f : denA;
      float invA = 1.f / dA;
      reinterpret_cast<float2*>(out)[nA * 32 + zoff] =
          make_float2(axA * invA + b2.x, ayA * invA + b2.y);
      if (hasB) {
        float dB = denB <= 0.f ? 1.f : denB;
        float invB = 1.f / dB;
        reinterpret_cast<float2*>(out)[nB * 32 + zoff] =
            make_float2(axB * invB + b2.x, ayB * invB + b2.y);
      }
    }
  }
}

extern "C" void kernel_launch(void* const* d_in, const int* in_sizes, int n_in,
                              void* d_out, int out_size, void* d_ws, size_t ws_size,
                              hipStream_t stream) {
  const float* feat = (const float*)d_in[0];
  const int* src = (const int*)d_in[1];
  const int* dst = (const int*)d_in[2];
  const float* Wm = (const float*)d_in[3];
  const float* attn = (const float*)d_in[4];
  const float* bias = (const float*)d_in[5];
  const int n = in_sizes[0] / DIN;
  const int e = in_sizes[1];
  float* out = (float*)d_out;

  // workspace layout (~28 MB)
  __half* zh = (__half*)d_ws;                      // n*64 halves (12.8MB)
  int* bkt = (int*)(zh + (size_t)n * HD);          // e ints (6.4MB, packed)
  float* el = (float*)(bkt + e);                   // n*4
  float* er = el + (size_t)n * NUM_H;              // n*4
  int* offs = (int*)(er + (size_t)n * NUM_H);      // n+1
  int* csr = offs + (n + 1);                       // e (6.4MB)
  int* mat = csr + e;                              // NCH*NBK (512KB)
  int* tot = mat + NCH * NBK;                      // NBK
  int* bbase = tot + NBK;                          // NBK+1

  const int PB = (n + 63) / 64;
  k_hist<<<NCH, 256, 0, stream>>>(dst, mat, e);
  k_scanA<<<NBK, 256, 0, stream>>>(mat, tot);
  k_scanB<<<1, NBK, 0, stream>>>(tot, bbase, offs, e, n);
  k_proj_bucket<<<NCH + PB, 256, 0, stream>>>(feat, Wm, attn, src, dst, mat,
                                              bbase, zh, el, er, bkt, n, e);
  int nbuckets = (n + (1 << BSH) - 1) >> BSH;
  k_csr<<<nbuckets, 256, 0, stream>>>(bkt, bbase, offs, csr, n);
  const int GB = 2048;
  k_gat<<<GB, 256, 0, stream>>>((const __half2*)zh, el, er, offs, csr, bias,
                                out, n, GB * 4);
}

// Round 16
// 126.872 us; speedup vs baseline: 1.1587x; 1.1587x over previous
//
#include <hip/hip_runtime.h>
#include <hip/hip_fp16.h>
#include <math.h>

#define NUM_H 4
#define HD 64
#define DIN 128
#define NEG_SLOPE 0.2f
#define LOG2E 1.4426950408889634f

#define NBK 512   // dst buckets (256 nodes each; 100k nodes -> 391 used)
#define BSH 8     // bucket shift
#define NCH 256   // edge chunks (R13 measured-best)
#define SRCB 17   // src fits 17 bits (n < 131072); loc uses bits 17..24

typedef _Float16 half8 __attribute__((ext_vector_type(8)));
typedef float f32x4 __attribute__((ext_vector_type(4)));

__device__ inline half8 pack8(float4 a, float4 b) {
  half8 h;
  h[0] = (_Float16)a.x; h[1] = (_Float16)a.y;
  h[2] = (_Float16)a.z; h[3] = (_Float16)a.w;
  h[4] = (_Float16)b.x; h[5] = (_Float16)b.y;
  h[6] = (_Float16)b.z; h[7] = (_Float16)b.w;
  return h;
}

// Pass 1: per-chunk LDS histogram over NBK dst-buckets (int4-vectorized),
// mat[chunk][bucket].
__global__ __launch_bounds__(256) void k_hist(const int* __restrict__ dst,
                                              int* __restrict__ mat, int e) {
  __shared__ int h[NBK];
  for (int i = threadIdx.x; i < NBK; i += 256) h[i] = 0;
  __syncthreads();
  const int chunk = (e + NCH - 1) / NCH;
  const int lo = blockIdx.x * chunk;
  const int hi = min(e, lo + chunk);
  const int lo4 = min(hi, (lo + 3) & ~3);
  const int hi4 = (hi & ~3) < lo4 ? lo4 : (hi & ~3);
  for (int i = lo + threadIdx.x; i < lo4; i += 256)
    atomicAdd(&h[dst[i] >> BSH], 1);
  for (int i = lo4 + threadIdx.x * 4; i < hi4; i += 1024) {
    int4 d4 = *reinterpret_cast<const int4*>(dst + i);
    atomicAdd(&h[d4.x >> BSH], 1);
    atomicAdd(&h[d4.y >> BSH], 1);
    atomicAdd(&h[d4.z >> BSH], 1);
    atomicAdd(&h[d4.w >> BSH], 1);
  }
  for (int i = hi4 + threadIdx.x; i < hi; i += 256)
    atomicAdd(&h[dst[i] >> BSH], 1);
  __syncthreads();
  for (int i = threadIdx.x; i < NBK; i += 256)
    mat[blockIdx.x * NBK + i] = h[i];
}

// Pass 2a (1 block per bucket): scan the bucket's NCH chunk-counts
// (LDS Hillis-Steele) -> per-(chunk,bucket) within-bucket starts + total.
__global__ __launch_bounds__(256) void k_scanA(int* __restrict__ mat,
                                               int* __restrict__ tot) {
  __shared__ int sm[NCH];
  const int b = blockIdx.x;
  const int t = threadIdx.x;
  int v = mat[t * NBK + b];
  sm[t] = v;
  __syncthreads();
  for (int off = 1; off < NCH; off <<= 1) {
    int x = (t >= off) ? sm[t - off] : 0;
    __syncthreads();
    sm[t] += x;
    __syncthreads();
  }
  mat[t * NBK + b] = sm[t] - v;  // exclusive within bucket
  if (t == NCH - 1) tot[b] = sm[t];
}

// Pass 2b (1 tiny block): exclusive scan of NBK bucket totals -> bbase.
__global__ __launch_bounds__(NBK) void k_scanB(const int* __restrict__ tot,
                                               int* __restrict__ bbase,
                                               int* __restrict__ offs,
                                               int e, int n) {
  __shared__ int sm[NBK];
  const int t = threadIdx.x;
  int v = tot[t];
  sm[t] = v;
  __syncthreads();
  for (int off = 1; off < NBK; off <<= 1) {
    int x = (t >= off) ? sm[t - off] : 0;
    __syncthreads();
    sm[t] += x;
    __syncthreads();
  }
  bbase[t] = sm[t] - v;
  if (t == NBK - 1) bbase[NBK] = sm[t];
  if (t == 0) offs[n] = e;
}

// ------- fused: bucket scatter (blocks < NCH) + projection via MFMA --------
// R13 measured-best arrangement. Bucket-role CHUNK SWIZZLE: within a bucket,
// runs are chunk-ordered; with chunk==blockIdx, adjacent runs are written by
// adjacent blocks on DIFFERENT XCDs (round-robin dispatch) -> every ~48B run
// boundary straddles a 64B line shared across non-coherent L2s -> double
// writebacks (R13 WRITE 34.7MB vs 6.4 ideal). cb=((blk&7)<<5)|(blk>>3) gives
// each XCD 32 consecutive chunks so adjacent runs share an L2 and merge.
__global__ __launch_bounds__(256) void k_proj_bucket(
    const float* __restrict__ feat, const float* __restrict__ Wm,
    const float* __restrict__ attn, const int* __restrict__ src,
    const int* __restrict__ dst, const int* __restrict__ mat,
    const int* __restrict__ bbase, __half* __restrict__ zh,
    float* __restrict__ el, float* __restrict__ er,
    int* __restrict__ bkt, int n, int e) {
  __shared__ int cur[NBK];
  if ((int)blockIdx.x < NCH) {
    const int cb = (((int)blockIdx.x & 7) << 5) | ((int)blockIdx.x >> 3);
    for (int i = threadIdx.x; i < NBK; i += 256)
      cur[i] = bbase[i] + mat[cb * NBK + i];
    __syncthreads();
    const int chunk = (e + NCH - 1) / NCH;
    const int lo = cb * chunk;
    const int hi = min(e, lo + chunk);
    const int lo4 = min(hi, (lo + 3) & ~3);
    const int hi4 = (hi & ~3) < lo4 ? lo4 : (hi & ~3);
    for (int i = lo + threadIdx.x; i < lo4; i += 256) {
      int d = dst[i];
      int p = atomicAdd(&cur[d >> BSH], 1);
      bkt[p] = ((d & ((1 << BSH) - 1)) << SRCB) | src[i];
    }
    for (int i = lo4 + threadIdx.x * 4; i < hi4; i += 1024) {
      int4 d4 = *reinterpret_cast<const int4*>(dst + i);
      int4 s4 = *reinterpret_cast<const int4*>(src + i);
      int p0 = atomicAdd(&cur[d4.x >> BSH], 1);
      bkt[p0] = ((d4.x & ((1 << BSH) - 1)) << SRCB) | s4.x;
      int p1 = atomicAdd(&cur[d4.y >> BSH], 1);
      bkt[p1] = ((d4.y & ((1 << BSH) - 1)) << SRCB) | s4.y;
      int p2 = atomicAdd(&cur[d4.z >> BSH], 1);
      bkt[p2] = ((d4.z & ((1 << BSH) - 1)) << SRCB) | s4.z;
      int p3 = atomicAdd(&cur[d4.w >> BSH], 1);
      bkt[p3] = ((d4.w & ((1 << BSH) - 1)) << SRCB) | s4.w;
    }
    for (int i = hi4 + threadIdx.x; i < hi; i += 256) {
      int d = dst[i];
      int p = atomicAdd(&cur[d >> BSH], 1);
      bkt[p] = ((d & ((1 << BSH) - 1)) << SRCB) | src[i];
    }
    return;
  }

  const int pb = (int)blockIdx.x - NCH;
  const int lane = threadIdx.x & 63;
  const int wv = threadIdx.x >> 6;
  const int l15 = lane & 15;
  const int g = lane >> 4;
  const int base = pb * 64 + wv * 16;

  half8 bf[4][4];  // [kt][j]
#pragma unroll
  for (int j = 0; j < 4; ++j) {
    const float* wp = Wm + (j * 16 + l15) * 128 + g * 8;
#pragma unroll
    for (int kt = 0; kt < 4; ++kt) {
      float4 w0 = *(const float4*)(wp + kt * 32);
      float4 w1 = *(const float4*)(wp + kt * 32 + 4);
      bf[kt][j] = pack8(w0, w1);
    }
  }

  int arow = base + l15;
  if (arow > n - 1) arow = n - 1;
  const float* fp = feat + (size_t)arow * 128 + g * 8;
  half8 af[4];
#pragma unroll
  for (int kt = 0; kt < 4; ++kt) {
    float4 a0 = *(const float4*)(fp + kt * 32);
    float4 a1 = *(const float4*)(fp + kt * 32 + 4);
    af[kt] = pack8(a0, a1);
  }

  f32x4 acc[4] = {{0.f,0.f,0.f,0.f},{0.f,0.f,0.f,0.f},
                  {0.f,0.f,0.f,0.f},{0.f,0.f,0.f,0.f}};
#pragma unroll
  for (int kt = 0; kt < 4; ++kt)
#pragma unroll
    for (int j = 0; j < 4; ++j)
      acc[j] = __builtin_amdgcn_mfma_f32_16x16x32_f16(af[kt], bf[kt][j], acc[j], 0, 0, 0);

  float a0v[4], a1v[4];
#pragma unroll
  for (int j = 0; j < 4; ++j) {
    a0v[j] = attn[j * 16 + l15];
    a1v[j] = attn[64 + j * 16 + l15];
  }
#pragma unroll
  for (int r = 0; r < 4; ++r) {
    int row = base + g * 4 + r;
    bool ok = row < n;
#pragma unroll
    for (int j = 0; j < 4; ++j) {
      float v = acc[j][r];
      if (ok) zh[(size_t)row * 64 + j * 16 + l15] = __float2half_rn(v);
      float pl = v * a0v[j];
      float pr = v * a1v[j];
#pragma unroll
      for (int o = 8; o >= 1; o >>= 1) {
        pl += __shfl_xor(pl, o, 16);
        pr += __shfl_xor(pr, o, 16);
      }
      if (ok && l15 == 0) {
        el[row * 4 + j] = pl * LOG2E;
        er[row * 4 + j] = pr * LOG2E;
      }
    }
  }
}

// Pass 4: one block per bucket (256 nodes): LDS node-histogram -> 8-step
// butterfly scan (1 node/thread) -> offs (coalesced) -> LDS-cursor scatter.
__global__ __launch_bounds__(256) void k_csr(
    const int* __restrict__ bkt, const int* __restrict__ bbase,
    int* __restrict__ offs, int* __restrict__ csr, int n) {
  __shared__ int h[1 << BSH];
  __shared__ int pre[1 << BSH];
  const int b = blockIdx.x;
  const int base = bbase[b];
  const int cnt = bbase[b + 1] - base;
  const int nlo = b << BSH;
  const int t = threadIdx.x;

  h[t] = 0;
  __syncthreads();
  for (int i = t; i < cnt; i += 256)
    atomicAdd(&h[bkt[base + i] >> SRCB], 1);
  __syncthreads();

  int v = h[t];
  pre[t] = v;
  __syncthreads();
  for (int off = 1; off < 256; off <<= 1) {
    int x = (t >= off) ? pre[t - off] : 0;
    __syncthreads();
    pre[t] += x;
    __syncthreads();
  }
  int excl = pre[t] - v;
  if (nlo + t < n) offs[nlo + t] = base + excl;
  h[t] = excl;  // reuse as cursor
  __syncthreads();
  for (int i = t; i < cnt; i += 256) {
    int w = bkt[base + i];
    int p = atomicAdd(&h[w >> SRCB], 1);
    csr[base + p] = w & ((1 << SRCB) - 1);
  }
}

// ---------------- fused segment softmax + weighted aggregate ----------------
// IDENTICAL to R10/R11/R13 (known-good 54.6us; both structural variants —
// R8 predicated-tail and R15 2-node-ILP — regressed). One wave per node,
// 4 heads in-wave, persistent grid-stride, 8-edge main blocks + step-2 tail,
// raw v_exp_f32 on log2e-prescaled logits.
__global__ __launch_bounds__(256) void k_gat(
    const __half2* __restrict__ zh, const float* __restrict__ el,
    const float* __restrict__ er, const int* __restrict__ offs,
    const int* __restrict__ csr, const float* __restrict__ bias,
    float* __restrict__ out, int n, int nwaves) {
  const int lane = threadIdx.x & 63;
  const int h = lane >> 4;
  const int slot = (lane >> 3) & 1;
  const int dp = lane & 7;
  const int gw = (blockIdx.x * 256 + threadIdx.x) >> 6;

  const float2 b2 = reinterpret_cast<const float2*>(bias)[h * 8 + dp];

  for (int node = gw; node < n; node += nwaves) {
    const int beg = offs[node], end = offs[node + 1];
    const float erh = er[node * 4 + h];
    float den = 0.f, ax = 0.f, ay = 0.f;

    int pb = beg;
    for (; pb + 8 <= end; pb += 8) {
      int q = pb + slot;
      int s0 = csr[q];
      int s1 = csr[q + 2];
      int s2 = csr[q + 4];
      int s3 = csr[q + 6];
      float x0 = el[s0 * 4 + h] + erh;
      float x1 = el[s1 * 4 + h] + erh;
      float x2 = el[s2 * 4 + h] + erh;
      float x3 = el[s3 * 4 + h] + erh;
      x0 = fmaxf(x0, x0 * NEG_SLOPE);
      x1 = fmaxf(x1, x1 * NEG_SLOPE);
      x2 = fmaxf(x2, x2 * NEG_SLOPE);
      x3 = fmaxf(x3, x3 * NEG_SLOPE);
      float e0 = __builtin_amdgcn_exp2f(x0);
      float e1 = __builtin_amdgcn_exp2f(x1);
      float e2 = __builtin_amdgcn_exp2f(x2);
      float e3 = __builtin_amdgcn_exp2f(x3);
      float2 z0 = __half22float2(zh[s0 * 32 + h * 8 + dp]);
      float2 z1 = __half22float2(zh[s1 * 32 + h * 8 + dp]);
      float2 z2 = __half22float2(zh[s2 * 32 + h * 8 + dp]);
      float2 z3 = __half22float2(zh[s3 * 32 + h * 8 + dp]);
      den += e0 + e1 + e2 + e3;
      ax += e0 * z0.x + e1 * z1.x + e2 * z2.x + e3 * z3.x;
      ay += e0 * z0.y + e1 * z1.y + e2 * z2.y + e3 * z3.y;
    }
    for (int q = pb + slot; q < end; q += 2) {
      int s0 = csr[q];
      float x0 = el[s0 * 4 + h] + erh;
      x0 = fmaxf(x0, x0 * NEG_SLOPE);
      float e0 = __builtin_amdgcn_exp2f(x0);
      float2 z0 = __half22float2(zh[s0 * 32 + h * 8 + dp]);
      den += e0;
      ax += e0 * z0.x;
      ay += e0 * z0.y;
    }

    den += __shfl_xor(den, 8);
    ax += __shfl_xor(ax, 8);
    ay += __shfl_xor(ay, 8);
    if (slot == 0) {
      float d = den <= 0.f ? 1.f : den;
      float inv = 1.f / d;
      float2 o2 = make_float2(ax * inv + b2.x, ay * inv + b2.y);
      reinterpret_cast<float2*>(out)[node * 32 + h * 8 + dp] = o2;
    }
  }
}

extern "C" void kernel_launch(void* const* d_in, const int* in_sizes, int n_in,
                              void* d_out, int out_size, void* d_ws, size_t ws_size,
                              hipStream_t stream) {
  const float* feat = (const float*)d_in[0];
  const int* src = (const int*)d_in[1];
  const int* dst = (const int*)d_in[2];
  const float* Wm = (const float*)d_in[3];
  const float* attn = (const float*)d_in[4];
  const float* bias = (const float*)d_in[5];
  const int n = in_sizes[0] / DIN;
  const int e = in_sizes[1];
  float* out = (float*)d_out;

  // workspace layout (~28 MB)
  __half* zh = (__half*)d_ws;                      // n*64 halves (12.8MB)
  int* bkt = (int*)(zh + (size_t)n * HD);          // e ints (6.4MB, packed)
  float* el = (float*)(bkt + e);                   // n*4
  float* er = el + (size_t)n * NUM_H;              // n*4
  int* offs = (int*)(er + (size_t)n * NUM_H);      // n+1
  int* csr = offs + (n + 1);                       // e (6.4MB)
  int* mat = csr + e;                              // NCH*NBK (512KB)
  int* tot = mat + NCH * NBK;                      // NBK
  int* bbase = tot + NBK;                          // NBK+1

  const int PB = (n + 63) / 64;
  k_hist<<<NCH, 256, 0, stream>>>(dst, mat, e);
  k_scanA<<<NBK, 256, 0, stream>>>(mat, tot);
  k_scanB<<<1, NBK, 0, stream>>>(tot, bbase, offs, e, n);
  k_proj_bucket<<<NCH + PB, 256, 0, stream>>>(feat, Wm, attn, src, dst, mat,
                                              bbase, zh, el, er, bkt, n, e);
  int nbuckets = (n + (1 << BSH) - 1) >> BSH;
  k_csr<<<nbuckets, 256, 0, stream>>>(bkt, bbase, offs, csr, n);
  const int GB = 2048;
  k_gat<<<GB, 256, 0, stream>>>((const __half2*)zh, el, er, offs, csr, bias,
                                out, n, GB * 4);
}